// Round 3
// baseline (290.717 us; speedup 1.0000x reference)
//
#include <hip/hip_runtime.h>

// Problem constants (from reference)
#define B_    16
#define C_    64
#define HW    36864          // 192*192
#define STEPS 65536          // P*L = 128*512 steps per batch
#define NBM   (HW / 32)      // 1152 bitmask dwords per batch
#define SPLIT 16             // touch blocks per batch
#define PXT   128            // pixels per mm block

typedef float f2 __attribute__((ext_vector_type(2)));

// ---------------------------------------------------------------------------
// Kernel 1: visited-pixel bitmask. Each block owns 4096 indices of one batch,
// builds a full 4.6KB LDS bitmask with ds-atomics, then merges into the
// global bitmask with ~1152 dword atomicOr (L2-resident, low contention).
// ---------------------------------------------------------------------------
__global__ __launch_bounds__(256) void touch_kernel(const int* __restrict__ idx,
                                                    unsigned int* __restrict__ gmask) {
    __shared__ unsigned int lm[NBM];
    const int t   = threadIdx.x;
    const int blk = blockIdx.x;
    const int b   = blk >> 4;   // SPLIT = 16
    const int s   = blk & 15;

    for (int i = t; i < NBM; i += 256) lm[i] = 0u;
    __syncthreads();

    const int4* p = (const int4*)idx + ((b * STEPS + s * (STEPS / SPLIT)) >> 2);
#pragma unroll
    for (int k = 0; k < 4; ++k) {
        int4 v = p[k * 256 + t];                      // coalesced 4KB per iter
        atomicOr(&lm[v.x >> 5], 1u << (v.x & 31));    // ds_or, races fine
        atomicOr(&lm[v.y >> 5], 1u << (v.y & 31));
        atomicOr(&lm[v.z >> 5], 1u << (v.z & 31));
        atomicOr(&lm[v.w >> 5], 1u << (v.w & 31));
    }
    __syncthreads();

    unsigned int* g = gmask + b * NBM;
    for (int i = t; i < NBM; i += 256) {
        unsigned int m = lm[i];
        if (m) atomicOr(&g[i], m);
    }
}

// ---------------------------------------------------------------------------
// Kernel 2: out[b, j, p] = visited(b,p) ? (sum_c feat[b,c,p] * W[c,j] + b[j]) : 0
// Block = 256 threads = 4 waves, owns 128 consecutive pixels (LDS 32 KB).
// Each lane owns a PIXEL PAIR (float2) -> v_pk_fma_f32 candidate, ds_read_b64,
// dwordx2 stores. Wave w computes output channels [w*16, w*16+16).
// ---------------------------------------------------------------------------
__global__ __launch_bounds__(256) void mm_mask_kernel(const float* __restrict__ feat,
                                                      const float* __restrict__ Wm,
                                                      const float* __restrict__ bm,
                                                      const unsigned int* __restrict__ gmask,
                                                      float* __restrict__ out) {
    __shared__ float ldsF[C_ * PXT];   // [channel][pixel], 32 KB

    const int t   = threadIdx.x;
    const int blk = blockIdx.x;
    const int b   = blk / (HW / PXT);
    const int hw0 = (blk % (HW / PXT)) * PXT;

    // ---- stage tile: 64 channels x 128 pixels, float4 coalesced ----
    const float* fbase = feat + (size_t)b * C_ * HW + hw0;
#pragma unroll
    for (int r = 0; r < 8; ++r) {
        int id = r * 256 + t;       // float4 id in [0,2048)
        int c  = id >> 5;           // 32 float4 per 128-px channel row
        int q  = id & 31;
        float4 v = *(const float4*)(fbase + (size_t)c * HW + q * 4);
        *(float4*)(&ldsF[c * PXT + q * 4]) = v;
    }
    __syncthreads();

    const int l  = t & 63;                                         // lane
    const int c0 = __builtin_amdgcn_readfirstlane((t >> 6) * 16);  // wave-uniform

    f2 acc[16];
#pragma unroll
    for (int i = 0; i < 16; ++i) { float bv = bm[c0 + i]; acc[i] = (f2){bv, bv}; }

    const f2* lds2 = (const f2*)ldsF;
#pragma unroll
    for (int kb = 0; kb < C_; kb += 4) {
        f2 f[4];
#pragma unroll
        for (int j = 0; j < 4; ++j) f[j] = lds2[(kb + j) * (PXT / 2) + l];  // ds_read_b64
#pragma unroll
        for (int j = 0; j < 4; ++j) {
            const float* wrow = Wm + (kb + j) * C_ + c0;   // wave-uniform -> s_load
#pragma unroll
            for (int i = 0; i < 16; ++i) {
                float w = wrow[i];
                acc[i] += f[j] * (f2){w, w};               // v_pk_fma_f32 candidate
            }
        }
    }

    // visited bits for pixel pair (2l, 2l+1)
    unsigned int m = gmask[b * NBM + (hw0 >> 5) + (l >> 4)];
    const int sh = (2 * l) & 31;
    f2 msk = (f2){ ((m >> sh) & 1u) ? 1.0f : 0.0f,
                   ((m >> (sh + 1)) & 1u) ? 1.0f : 0.0f };

    float* obase = out + (size_t)b * C_ * HW + hw0 + 2 * l;
#pragma unroll
    for (int i = 0; i < 16; ++i) {
        f2 r = acc[i] * msk;
        *(f2*)(obase + (size_t)(c0 + i) * HW) = r;         // 512B coalesced per row
    }
}

// ---------------------------------------------------------------------------
extern "C" void kernel_launch(void* const* d_in, const int* in_sizes, int n_in,
                              void* d_out, int out_size, void* d_ws, size_t ws_size,
                              hipStream_t stream) {
    const float*   feat  = (const float*)d_in[0];
    const int*     idx   = (const int*)d_in[1];
    const float*   Wm    = (const float*)d_in[2];
    const float*   bm    = (const float*)d_in[3];
    float*         out   = (float*)d_out;
    unsigned int*  gmask = (unsigned int*)d_ws;

    // zero the visited bitmask (B * 1152 dwords = 73,728 B)
    hipMemsetAsync(gmask, 0, (size_t)B_ * NBM * sizeof(unsigned int), stream);

    // build bitmask: 16 batches x 16 splits
    touch_kernel<<<B_ * SPLIT, 256, 0, stream>>>(idx, gmask);

    // masked per-pixel linear transform
    mm_mask_kernel<<<B_ * (HW / PXT), 256, 0, stream>>>(feat, Wm, bm, gmask, out);
}